// Round 3
// baseline (220.628 us; speedup 1.0000x reference)
//
#include <hip/hip_runtime.h>
#include <hip/hip_bf16.h>
#include <stdint.h>

#define BDIM 2048
#define HDIM 1024
#define XDIM 1024
#define BH (BDIM*HDIM)
#define WSEG 1048576  // 1024*1024 elements per weight matrix

typedef __attribute__((ext_vector_type(8))) short short8;
typedef __attribute__((ext_vector_type(4))) float float4v;

__device__ __forceinline__ void gload16(const void* g, void* l) {
    __builtin_amdgcn_global_load_lds(
        (const __attribute__((address_space(1))) unsigned int*)g,
        (__attribute__((address_space(3))) unsigned int*)l, 16, 0, 0);
}

__device__ __forceinline__ unsigned pack2(float a, float b) {
    __hip_bfloat162 v = __float22bfloat162_rn(make_float2(a, b));
    return *reinterpret_cast<unsigned*>(&v);
}
__device__ __forceinline__ uint2 pack4(float4 f) {
    return make_uint2(pack2(f.x, f.y), pack2(f.z, f.w));
}

// ---------------- cvt: fp32 -> bf16 for 8 weights + x (10 segments of 1M elems) ----------------
__global__ __launch_bounds__(256) void cvt_k(
    const float* __restrict__ w0, const float* __restrict__ w1,
    const float* __restrict__ w2, const float* __restrict__ w3,
    const float* __restrict__ w4, const float* __restrict__ w5,
    const float* __restrict__ w6, const float* __restrict__ w7,
    const float* __restrict__ x, uint2* __restrict__ dst) {
    const int seg = blockIdx.y;
    const int i = blockIdx.x * 256 + threadIdx.x;   // float4 index within segment (262144)
    const float* base;
    switch (seg) {
        case 0: base = w0; break; case 1: base = w1; break;
        case 2: base = w2; break; case 3: base = w3; break;
        case 4: base = w4; break; case 5: base = w5; break;
        case 6: base = w6; break; case 7: base = w7; break;
        default: base = x + (size_t)(seg - 8) * WSEG; break;
    }
    float4 f = ((const float4*)base)[i];
    dst[(size_t)seg * (WSEG / 4) + i] = pack4(f);
}

// ---------------- prep: hm[g] = bf16(h0 * maskHg) ----------------
__global__ __launch_bounds__(256) void prep_hm_k(
    const float4* __restrict__ h0, const float4* __restrict__ mI,
    const float4* __restrict__ mF, const float4* __restrict__ mC,
    const float4* __restrict__ mO, uint2* __restrict__ hm) {
    const int i = blockIdx.x * 256 + threadIdx.x;   // float4 index over BH/4
    float4 h = h0[i];
    float4 a = mI[i], b = mF[i], c = mC[i], d = mO[i];
    hm[0 * (BH / 4) + i] = pack4(make_float4(h.x * a.x, h.y * a.y, h.z * a.z, h.w * a.w));
    hm[1 * (BH / 4) + i] = pack4(make_float4(h.x * b.x, h.y * b.y, h.z * b.z, h.w * b.w));
    hm[2 * (BH / 4) + i] = pack4(make_float4(h.x * c.x, h.y * c.y, h.z * c.z, h.w * c.w));
    hm[3 * (BH / 4) + i] = pack4(make_float4(h.x * d.x, h.y * d.y, h.z * d.z, h.w * d.w));
}

// ---------------- gemm: pre[g][b][n] = xb[b,:]·wx_g[n,:] + hm_g[b,:]·wh_g[n,:] ----------------
// 128x128 tile, BK=32, 256 threads (4 waves 2x2), 4x4 of 16x16x32 bf16 MFMA per wave (m97 structure).
__global__ __launch_bounds__(256) void gemm_gates(
    const __hip_bfloat16* __restrict__ wb,   // 8 x 1M bf16: wxi..wxo, whi..who
    const __hip_bfloat16* __restrict__ xb,   // 2M bf16
    const __hip_bfloat16* __restrict__ hm,   // 4 x 2M bf16
    float* __restrict__ pre) {
    const int g = blockIdx.z;
    const __hip_bfloat16* wx = wb + (size_t)g * WSEG;
    const __hip_bfloat16* wh = wb + (size_t)(4 + g) * WSEG;
    const __hip_bfloat16* A2 = hm + (size_t)g * BH;

    __shared__ __hip_bfloat16 As[128 * 32];
    __shared__ __hip_bfloat16 Bs[128 * 32];

    const int t = threadIdx.x;
    const int m0 = blockIdx.x * 128;
    const int n0 = blockIdx.y * 128;
    const int wv = t >> 6, lane = t & 63;
    const int wm = (wv >> 1) * 64, wn = (wv & 1) * 64;
    const int quad = lane >> 4, lrow = lane & 15;

    float4v acc[4][4];
#pragma unroll
    for (int i = 0; i < 4; ++i)
#pragma unroll
        for (int j = 0; j < 4; ++j) acc[i][j] = (float4v){0.f, 0.f, 0.f, 0.f};

    const short8* As8 = (const short8*)As;
    const short8* Bs8 = (const short8*)Bs;

#pragma unroll 1
    for (int half = 0; half < 2; ++half) {
        const __hip_bfloat16* Ap = half ? A2 : xb;
        const __hip_bfloat16* Bp = half ? wh : wx;
        for (int k0 = 0; k0 < 1024; k0 += 32) {
#pragma unroll
            for (int it = 0; it < 2; ++it) {
                int chunk = it * 256 + t;
                int row = chunk >> 2, cc = chunk & 3;
                gload16(Ap + (size_t)(m0 + row) * 1024 + k0 + cc * 8,
                        (char*)As + chunk * 16);
                gload16(Bp + (size_t)(n0 + row) * 1024 + k0 + cc * 8,
                        (char*)Bs + chunk * 16);
            }
            __syncthreads();

            short8 af[4], bfr[4];
#pragma unroll
            for (int mt = 0; mt < 4; ++mt) af[mt] = As8[(wm + mt * 16 + lrow) * 4 + quad];
#pragma unroll
            for (int nt = 0; nt < 4; ++nt) bfr[nt] = Bs8[(wn + nt * 16 + lrow) * 4 + quad];
#pragma unroll
            for (int mt = 0; mt < 4; ++mt)
#pragma unroll
                for (int nt = 0; nt < 4; ++nt)
                    acc[mt][nt] = __builtin_amdgcn_mfma_f32_16x16x32_bf16(
                        af[mt], bfr[nt], acc[mt][nt], 0, 0, 0);
            __syncthreads();
        }
    }

    // epilogue: C/D layout col=lane&15, row=quad*4+r (m89/m91 verified)
    float* preg = pre + (size_t)g * BH;
#pragma unroll
    for (int mt = 0; mt < 4; ++mt) {
#pragma unroll
        for (int nt = 0; nt < 4; ++nt) {
            int col = n0 + wn + nt * 16 + lrow;
#pragma unroll
            for (int r = 0; r < 4; ++r) {
                int row = m0 + wm + mt * 16 + quad * 4 + r;
                preg[(size_t)row * HDIM + col] = acc[mt][nt][r];
            }
        }
    }
}

// ---------------- combine: gates -> h1, c1 (fp32 out: h1 then c1) ----------------
__global__ __launch_bounds__(256) void combine_k(
    const float* __restrict__ pre,
    const float* __restrict__ bi, const float* __restrict__ bff,
    const float* __restrict__ bc, const float* __restrict__ bo,
    const float* __restrict__ c0, const float* __restrict__ mC,
    float4* __restrict__ out) {
    const int i = blockIdx.x * 256 + threadIdx.x;   // float4 index over BH/4
    const int i4 = i * 4;
    const int h4 = (i4 & (HDIM - 1)) >> 2;          // float4 index into biases
    float4 gi = ((const float4*)pre)[i];
    float4 gf = ((const float4*)(pre + BH))[i];
    float4 gc = ((const float4*)(pre + 2 * (size_t)BH))[i];
    float4 go = ((const float4*)(pre + 3 * (size_t)BH))[i];
    float4 vbi = ((const float4*)bi)[h4];
    float4 vbf = ((const float4*)bff)[h4];
    float4 vbc = ((const float4*)bc)[h4];
    float4 vbo = ((const float4*)bo)[h4];
    float4 vc0 = ((const float4*)c0)[i];
    float4 vmc = ((const float4*)mC)[i];

    float h1[4], c1[4];
#pragma unroll
    for (int j = 0; j < 4; ++j) {
        float xi = (j == 0) ? gi.x + vbi.x : (j == 1) ? gi.y + vbi.y : (j == 2) ? gi.z + vbi.z : gi.w + vbi.w;
        float xf = (j == 0) ? gf.x + vbf.x : (j == 1) ? gf.y + vbf.y : (j == 2) ? gf.z + vbf.z : gf.w + vbf.w;
        float xc = (j == 0) ? gc.x + vbc.x : (j == 1) ? gc.y + vbc.y : (j == 2) ? gc.z + vbc.z : gc.w + vbc.w;
        float xo = (j == 0) ? go.x + vbo.x : (j == 1) ? go.y + vbo.y : (j == 2) ? go.z + vbo.z : go.w + vbo.w;
        float cc0 = (j == 0) ? vc0.x : (j == 1) ? vc0.y : (j == 2) ? vc0.z : vc0.w;
        float mm = (j == 0) ? vmc.x : (j == 1) ? vmc.y : (j == 2) ? vmc.z : vmc.w;
        float I = 1.f / (1.f + __expf(-xi));
        float F = 1.f / (1.f + __expf(-xf));
        float C = tanhf(xc) * mm;
        float O = 1.f / (1.f + __expf(-xo));
        c1[j] = F * cc0 + I * C;
        h1[j] = O * tanhf(c1[j]);
    }
    out[i] = make_float4(h1[0], h1[1], h1[2], h1[3]);
    out[BH / 4 + i] = make_float4(c1[0], c1[1], c1[2], c1[3]);
}

extern "C" void kernel_launch(void* const* d_in, const int* in_sizes, int n_in,
                              void* d_out, int out_size, void* d_ws, size_t ws_size,
                              hipStream_t stream) {
    const float* x   = (const float*)d_in[0];
    const float* h0  = (const float*)d_in[1];
    const float* c0  = (const float*)d_in[2];
    const float* wxi = (const float*)d_in[3];
    const float* wxf = (const float*)d_in[4];
    const float* wxc = (const float*)d_in[5];
    const float* wxo = (const float*)d_in[6];
    const float* whi = (const float*)d_in[7];
    const float* whf = (const float*)d_in[8];
    const float* whc = (const float*)d_in[9];
    const float* who = (const float*)d_in[10];
    const float* bi  = (const float*)d_in[11];
    const float* bf  = (const float*)d_in[12];
    const float* bc  = (const float*)d_in[13];
    const float* bo  = (const float*)d_in[14];
    const float* mI  = (const float*)d_in[15];
    const float* mF  = (const float*)d_in[16];
    const float* mC  = (const float*)d_in[17];
    const float* mO  = (const float*)d_in[18];
    const float* mCell = (const float*)d_in[19];

    // ws layout (bytes): wb[8*1M bf16]=16MB | xb[2M bf16]=4MB | hm[4*2M bf16]=16MB | pre[8M f32]=32MB
    __hip_bfloat16* wb = (__hip_bfloat16*)d_ws;
    __hip_bfloat16* xb = wb + (size_t)8 * WSEG;
    __hip_bfloat16* hm = xb + (size_t)2 * WSEG;
    float* pre = (float*)(hm + (size_t)4 * BH);

    // convert weights + x to bf16 (10 segments of 1M elems; segs 8,9 are x)
    cvt_k<<<dim3(WSEG / 4 / 256, 10), dim3(256), 0, stream>>>(
        wxi, wxf, wxc, wxo, whi, whf, whc, who, x, (uint2*)wb);

    prep_hm_k<<<dim3(BH / 4 / 256), dim3(256), 0, stream>>>(
        (const float4*)h0, (const float4*)mI, (const float4*)mF,
        (const float4*)mC, (const float4*)mO, (uint2*)hm);

    gemm_gates<<<dim3(BDIM / 128, HDIM / 128, 4), dim3(256), 0, stream>>>(
        wb, xb, hm, pre);

    combine_k<<<dim3(BH / 4 / 256), dim3(256), 0, stream>>>(
        pre, bi, bf, bc, bo, c0, mCell, (float4*)d_out);
}

// Round 4
// 215.511 us; speedup vs baseline: 1.0237x; 1.0237x over previous
//
#include <hip/hip_runtime.h>
#include <hip/hip_bf16.h>
#include <stdint.h>

#define BDIM 2048
#define HDIM 1024
#define XDIM 1024
#define BH (BDIM*HDIM)
#define WSEG 1048576  // 1M elements per segment

typedef __attribute__((ext_vector_type(8))) short short8;
typedef __attribute__((ext_vector_type(4))) float float4v;

__device__ __forceinline__ void gload16(const void* g, void* l) {
    __builtin_amdgcn_global_load_lds(
        (const __attribute__((address_space(1))) unsigned int*)g,
        (__attribute__((address_space(3))) unsigned int*)l, 16, 0, 0);
}

__device__ __forceinline__ unsigned pack2(float a, float b) {
    __hip_bfloat162 v = __float22bfloat162_rn(make_float2(a, b));
    return *reinterpret_cast<unsigned*>(&v);
}
__device__ __forceinline__ uint2 pack4(float4 f) {
    return make_uint2(pack2(f.x, f.y), pack2(f.z, f.w));
}

// ---------------- prep_all: fp32 -> bf16 for everything the GEMM eats ----------------
// ws bf16 segment map (1M elems each):
//   segs 0..7  : wxi,wxf,wxc,wxo,whi,whf,whc,who
//   segs 8..9  : x (rows 0..1023, 1024..2047)
//   segs 10..17: hm[g][half] = h0[half] * maskHg[half]   (g-major, halves contiguous)
__global__ __launch_bounds__(256) void prep_all_k(
    const float* __restrict__ w0, const float* __restrict__ w1,
    const float* __restrict__ w2, const float* __restrict__ w3,
    const float* __restrict__ w4, const float* __restrict__ w5,
    const float* __restrict__ w6, const float* __restrict__ w7,
    const float* __restrict__ x, const float* __restrict__ h0,
    const float* __restrict__ mI, const float* __restrict__ mF,
    const float* __restrict__ mC, const float* __restrict__ mO,
    uint2* __restrict__ dst) {
    const int seg = blockIdx.y;
    const int i = blockIdx.x * 256 + threadIdx.x;   // float4 index within segment (262144)
    float4 f;
    if (seg < 10) {
        const float* base;
        switch (seg) {
            case 0: base = w0; break; case 1: base = w1; break;
            case 2: base = w2; break; case 3: base = w3; break;
            case 4: base = w4; break; case 5: base = w5; break;
            case 6: base = w6; break; case 7: base = w7; break;
            default: base = x + (size_t)(seg - 8) * WSEG; break;
        }
        f = ((const float4*)base)[i];
    } else {
        const int s = seg - 10;
        const int g = s >> 1, half = s & 1;
        const float* mp = (g == 0) ? mI : (g == 1) ? mF : (g == 2) ? mC : mO;
        float4 h = ((const float4*)(h0 + (size_t)half * WSEG))[i];
        float4 m = ((const float4*)(mp + (size_t)half * WSEG))[i];
        f = make_float4(h.x * m.x, h.y * m.y, h.z * m.z, h.w * m.w);
    }
    dst[(size_t)seg * (WSEG / 4) + i] = pack4(f);
}

// ---------------- gemm: pre[g][b][n] = x[b,:]·wx_g[n,:] + hm_g[b,:]·wh_g[n,:] + b_g[n] ----------------
// 128x128 tile, BK=32, 256 threads (4 waves 2x2), 4x4 of 16x16x32 bf16 MFMA per wave (m97 structure).
__global__ __launch_bounds__(256) void gemm_gates(
    const __hip_bfloat16* __restrict__ ws18,  // 18 x 1M bf16 per prep_all map
    const float* __restrict__ bi, const float* __restrict__ bff,
    const float* __restrict__ bc, const float* __restrict__ bo,
    float* __restrict__ pre) {
    const int g = blockIdx.z;
    const __hip_bfloat16* wx = ws18 + (size_t)g * WSEG;
    const __hip_bfloat16* wh = ws18 + (size_t)(4 + g) * WSEG;
    const __hip_bfloat16* xb = ws18 + (size_t)8 * WSEG;
    const __hip_bfloat16* A2 = ws18 + (size_t)(10 + 2 * g) * WSEG;
    const float* bg = (g == 0) ? bi : (g == 1) ? bff : (g == 2) ? bc : bo;

    __shared__ __hip_bfloat16 As[128 * 32];
    __shared__ __hip_bfloat16 Bs[128 * 32];

    const int t = threadIdx.x;
    const int m0 = blockIdx.x * 128;
    const int n0 = blockIdx.y * 128;
    const int wv = t >> 6, lane = t & 63;
    const int wm = (wv >> 1) * 64, wn = (wv & 1) * 64;
    const int quad = lane >> 4, lrow = lane & 15;

    float4v acc[4][4];
#pragma unroll
    for (int i = 0; i < 4; ++i)
#pragma unroll
        for (int j = 0; j < 4; ++j) acc[i][j] = (float4v){0.f, 0.f, 0.f, 0.f};

    const short8* As8 = (const short8*)As;
    const short8* Bs8 = (const short8*)Bs;

#pragma unroll 1
    for (int half = 0; half < 2; ++half) {
        const __hip_bfloat16* Ap = half ? A2 : xb;
        const __hip_bfloat16* Bp = half ? wh : wx;
        for (int k0 = 0; k0 < 1024; k0 += 32) {
#pragma unroll
            for (int it = 0; it < 2; ++it) {
                int chunk = it * 256 + t;
                int row = chunk >> 2, cc = chunk & 3;
                gload16(Ap + (size_t)(m0 + row) * 1024 + k0 + cc * 8,
                        (char*)As + chunk * 16);
                gload16(Bp + (size_t)(n0 + row) * 1024 + k0 + cc * 8,
                        (char*)Bs + chunk * 16);
            }
            __syncthreads();

            short8 af[4], bfr[4];
#pragma unroll
            for (int mt = 0; mt < 4; ++mt) af[mt] = As8[(wm + mt * 16 + lrow) * 4 + quad];
#pragma unroll
            for (int nt = 0; nt < 4; ++nt) bfr[nt] = Bs8[(wn + nt * 16 + lrow) * 4 + quad];
#pragma unroll
            for (int mt = 0; mt < 4; ++mt)
#pragma unroll
                for (int nt = 0; nt < 4; ++nt)
                    acc[mt][nt] = __builtin_amdgcn_mfma_f32_16x16x32_bf16(
                        af[mt], bfr[nt], acc[mt][nt], 0, 0, 0);
            __syncthreads();
        }
    }

    // epilogue: C/D layout col=lane&15, row=quad*4+r (m89/m91 verified); bias fused
    float* preg = pre + (size_t)g * BH;
#pragma unroll
    for (int nt = 0; nt < 4; ++nt) {
        int col = n0 + wn + nt * 16 + lrow;
        float bias = bg[col];
#pragma unroll
        for (int mt = 0; mt < 4; ++mt) {
#pragma unroll
            for (int r = 0; r < 4; ++r) {
                int row = m0 + wm + mt * 16 + quad * 4 + r;
                preg[(size_t)row * HDIM + col] = acc[mt][nt][r] + bias;
            }
        }
    }
}

// ---------------- combine: gates -> h1, c1 (fp32 out: h1 then c1) ----------------
__global__ __launch_bounds__(256) void combine_k(
    const float* __restrict__ pre,
    const float* __restrict__ c0, const float* __restrict__ mC,
    float4* __restrict__ out) {
    const int i = blockIdx.x * 256 + threadIdx.x;   // float4 index over BH/4
    float4 gi = ((const float4*)pre)[i];
    float4 gf = ((const float4*)(pre + BH))[i];
    float4 gc = ((const float4*)(pre + 2 * (size_t)BH))[i];
    float4 go = ((const float4*)(pre + 3 * (size_t)BH))[i];
    float4 vc0 = ((const float4*)c0)[i];
    float4 vmc = ((const float4*)mC)[i];

    float h1[4], c1[4];
#pragma unroll
    for (int j = 0; j < 4; ++j) {
        float xi = (j == 0) ? gi.x : (j == 1) ? gi.y : (j == 2) ? gi.z : gi.w;
        float xf = (j == 0) ? gf.x : (j == 1) ? gf.y : (j == 2) ? gf.z : gf.w;
        float xc = (j == 0) ? gc.x : (j == 1) ? gc.y : (j == 2) ? gc.z : gc.w;
        float xo = (j == 0) ? go.x : (j == 1) ? go.y : (j == 2) ? go.z : go.w;
        float cc0 = (j == 0) ? vc0.x : (j == 1) ? vc0.y : (j == 2) ? vc0.z : vc0.w;
        float mm = (j == 0) ? vmc.x : (j == 1) ? vmc.y : (j == 2) ? vmc.z : vmc.w;
        float I = 1.f / (1.f + __expf(-xi));
        float F = 1.f / (1.f + __expf(-xf));
        float C = tanhf(xc) * mm;
        float O = 1.f / (1.f + __expf(-xo));
        c1[j] = F * cc0 + I * C;
        h1[j] = O * tanhf(c1[j]);
    }
    out[i] = make_float4(h1[0], h1[1], h1[2], h1[3]);
    out[BH / 4 + i] = make_float4(c1[0], c1[1], c1[2], c1[3]);
}

extern "C" void kernel_launch(void* const* d_in, const int* in_sizes, int n_in,
                              void* d_out, int out_size, void* d_ws, size_t ws_size,
                              hipStream_t stream) {
    const float* x   = (const float*)d_in[0];
    const float* h0  = (const float*)d_in[1];
    const float* c0  = (const float*)d_in[2];
    const float* wxi = (const float*)d_in[3];
    const float* wxf = (const float*)d_in[4];
    const float* wxc = (const float*)d_in[5];
    const float* wxo = (const float*)d_in[6];
    const float* whi = (const float*)d_in[7];
    const float* whf = (const float*)d_in[8];
    const float* whc = (const float*)d_in[9];
    const float* who = (const float*)d_in[10];
    const float* bi  = (const float*)d_in[11];
    const float* bf  = (const float*)d_in[12];
    const float* bc  = (const float*)d_in[13];
    const float* bo  = (const float*)d_in[14];
    const float* mI  = (const float*)d_in[15];
    const float* mF  = (const float*)d_in[16];
    const float* mC  = (const float*)d_in[17];
    const float* mO  = (const float*)d_in[18];
    const float* mCell = (const float*)d_in[19];

    // ws layout: 18*1M bf16 = 36 MB | pre: 4*BH f32 = 32 MB
    __hip_bfloat16* ws18 = (__hip_bfloat16*)d_ws;
    float* pre = (float*)(ws18 + (size_t)18 * WSEG);

    prep_all_k<<<dim3(WSEG / 4 / 256, 18), dim3(256), 0, stream>>>(
        wxi, wxf, wxc, wxo, whi, whf, whc, who, x, h0, mI, mF, mC, mO,
        (uint2*)ws18);

    gemm_gates<<<dim3(BDIM / 128, HDIM / 128, 4), dim3(256), 0, stream>>>(
        ws18, bi, bf, bc, bo, pre);

    combine_k<<<dim3(BH / 4 / 256), dim3(256), 0, stream>>>(
        pre, c0, mCell, (float4*)d_out);
}

// Round 5
// 213.905 us; speedup vs baseline: 1.0314x; 1.0075x over previous
//
#include <hip/hip_runtime.h>
#include <hip/hip_bf16.h>
#include <stdint.h>

#define BDIM 2048
#define HDIM 1024
#define XDIM 1024
#define BH (BDIM*HDIM)
#define WSEG 1048576  // 1M elements per segment

typedef __attribute__((ext_vector_type(8))) short short8;
typedef __attribute__((ext_vector_type(4))) float float4v;

__device__ __forceinline__ void gload16(const void* g, void* l) {
    __builtin_amdgcn_global_load_lds(
        (const __attribute__((address_space(1))) unsigned int*)g,
        (__attribute__((address_space(3))) unsigned int*)l, 16, 0, 0);
}

__device__ __forceinline__ unsigned pack2(float a, float b) {
    __hip_bfloat162 v = __float22bfloat162_rn(make_float2(a, b));
    return *reinterpret_cast<unsigned*>(&v);
}
__device__ __forceinline__ uint2 pack4(float4 f) {
    return make_uint2(pack2(f.x, f.y), pack2(f.z, f.w));
}
__device__ __forceinline__ float2 up2(unsigned u) {
    __hip_bfloat162 v = *reinterpret_cast<__hip_bfloat162*>(&u);
    return __bfloat1622float2(v);
}

// ---------------- prep_all: fp32 -> bf16 for everything the GEMM eats ----------------
// ws bf16 segment map (1M elems each):
//   segs 0..7  : wxi,wxf,wxc,wxo,whi,whf,whc,who
//   segs 8..9  : x (rows 0..1023, 1024..2047)
//   segs 10..17: hm[g][rowhalf] = h0 * maskHg   (hm_g contiguous as 2048x1024)
__global__ __launch_bounds__(256) void prep_all_k(
    const float* __restrict__ w0, const float* __restrict__ w1,
    const float* __restrict__ w2, const float* __restrict__ w3,
    const float* __restrict__ w4, const float* __restrict__ w5,
    const float* __restrict__ w6, const float* __restrict__ w7,
    const float* __restrict__ x, const float* __restrict__ h0,
    const float* __restrict__ mI, const float* __restrict__ mF,
    const float* __restrict__ mC, const float* __restrict__ mO,
    uint2* __restrict__ dst) {
    const int seg = blockIdx.y;
    const int i = blockIdx.x * 256 + threadIdx.x;   // float4 index within segment (262144)
    float4 f;
    if (seg < 10) {
        const float* base;
        switch (seg) {
            case 0: base = w0; break; case 1: base = w1; break;
            case 2: base = w2; break; case 3: base = w3; break;
            case 4: base = w4; break; case 5: base = w5; break;
            case 6: base = w6; break; case 7: base = w7; break;
            default: base = x + (size_t)(seg - 8) * WSEG; break;
        }
        f = ((const float4*)base)[i];
    } else {
        const int s = seg - 10;
        const int g = s >> 1, half = s & 1;
        const float* mp = (g == 0) ? mI : (g == 1) ? mF : (g == 2) ? mC : mO;
        float4 h = ((const float4*)(h0 + (size_t)half * WSEG))[i];
        float4 m = ((const float4*)(mp + (size_t)half * WSEG))[i];
        f = make_float4(h.x * m.x, h.y * m.y, h.z * m.z, h.w * m.w);
    }
    dst[(size_t)seg * (WSEG / 4) + i] = pack4(f);
}

// ---------------- gemm split-K: part[z=2g+half][b][n] = A_half[b,:]·B_gh[n,:]  (bf16 out) ----------------
// z=2g+half: half=0 -> A=x, B=wx_g ; half=1 -> A=hm_g, B=wh_g.  K=1024 per block.
// 128x128 tile, BK=32, 256 threads (4 waves 2x2), 4x4 of 16x16x32 bf16 MFMA (m97 structure).
__global__ __launch_bounds__(256, 4) void gemm_split(
    const __hip_bfloat16* __restrict__ ws18,  // 18 x 1M bf16 per prep_all map
    __hip_bfloat16* __restrict__ part) {      // 8 x BH bf16
    const int z = blockIdx.z;
    const int g = z >> 1, half = z & 1;
    const __hip_bfloat16* Ap = half ? (ws18 + (size_t)(10 + 2 * g) * WSEG)
                                    : (ws18 + (size_t)8 * WSEG);
    const __hip_bfloat16* Bp = half ? (ws18 + (size_t)(4 + g) * WSEG)
                                    : (ws18 + (size_t)g * WSEG);

    __shared__ __hip_bfloat16 As[128 * 32];
    __shared__ __hip_bfloat16 Bs[128 * 32];

    const int t = threadIdx.x;
    const int m0 = blockIdx.x * 128;
    const int n0 = blockIdx.y * 128;
    const int wv = t >> 6, lane = t & 63;
    const int wm = (wv >> 1) * 64, wn = (wv & 1) * 64;
    const int quad = lane >> 4, lrow = lane & 15;

    float4v acc[4][4];
#pragma unroll
    for (int i = 0; i < 4; ++i)
#pragma unroll
        for (int j = 0; j < 4; ++j) acc[i][j] = (float4v){0.f, 0.f, 0.f, 0.f};

    const short8* As8 = (const short8*)As;
    const short8* Bs8 = (const short8*)Bs;

    for (int k0 = 0; k0 < 1024; k0 += 32) {
#pragma unroll
        for (int it = 0; it < 2; ++it) {
            int chunk = it * 256 + t;
            int row = chunk >> 2, cc = chunk & 3;
            gload16(Ap + (size_t)(m0 + row) * 1024 + k0 + cc * 8,
                    (char*)As + chunk * 16);
            gload16(Bp + (size_t)(n0 + row) * 1024 + k0 + cc * 8,
                    (char*)Bs + chunk * 16);
        }
        __syncthreads();

        short8 af[4], bfr[4];
#pragma unroll
        for (int mt = 0; mt < 4; ++mt) af[mt] = As8[(wm + mt * 16 + lrow) * 4 + quad];
#pragma unroll
        for (int nt = 0; nt < 4; ++nt) bfr[nt] = Bs8[(wn + nt * 16 + lrow) * 4 + quad];
#pragma unroll
        for (int mt = 0; mt < 4; ++mt)
#pragma unroll
            for (int nt = 0; nt < 4; ++nt)
                acc[mt][nt] = __builtin_amdgcn_mfma_f32_16x16x32_bf16(
                    af[mt], bfr[nt], acc[mt][nt], 0, 0, 0);
        __syncthreads();
    }

    // epilogue: C/D layout col=lane&15, row=quad*4+r (m89/m91 verified); bf16 partial
    __hip_bfloat16* pz = part + (size_t)z * BH;
#pragma unroll
    for (int nt = 0; nt < 4; ++nt) {
        int col = n0 + wn + nt * 16 + lrow;
#pragma unroll
        for (int mt = 0; mt < 4; ++mt) {
#pragma unroll
            for (int r = 0; r < 4; ++r) {
                int row = m0 + wm + mt * 16 + quad * 4 + r;
                pz[(size_t)row * HDIM + col] = __float2bfloat16(acc[mt][nt][r]);
            }
        }
    }
}

// ---------------- combine: sum split-K partials + bias -> gates -> h1, c1 (fp32 out) ----------------
__global__ __launch_bounds__(256) void combine_k(
    const uint2* __restrict__ part,   // 8 x BH bf16, as uint2 = 4 elems
    const float* __restrict__ bi, const float* __restrict__ bff,
    const float* __restrict__ bc, const float* __restrict__ bo,
    const float* __restrict__ c0, const float* __restrict__ mC,
    float4* __restrict__ out) {
    const int i = blockIdx.x * 256 + threadIdx.x;   // 4-elem group index over BH/4
    const int h4 = (i * 4 & (HDIM - 1)) >> 2;       // float4 index into biases

    float gate[4][4];
#pragma unroll
    for (int g = 0; g < 4; ++g) {
        uint2 p0 = part[(size_t)(2 * g) * (BH / 4) + i];
        uint2 p1 = part[(size_t)(2 * g + 1) * (BH / 4) + i];
        float2 a0 = up2(p0.x), a1 = up2(p0.y);
        float2 b0 = up2(p1.x), b1 = up2(p1.y);
        gate[g][0] = a0.x + b0.x;
        gate[g][1] = a0.y + b0.y;
        gate[g][2] = a1.x + b1.x;
        gate[g][3] = a1.y + b1.y;
    }
    float4 vbi = ((const float4*)bi)[h4];
    float4 vbf = ((const float4*)bff)[h4];
    float4 vbc = ((const float4*)bc)[h4];
    float4 vbo = ((const float4*)bo)[h4];
    float4 vc0 = ((const float4*)c0)[i];
    float4 vmc = ((const float4*)mC)[i];
    const float* pbi = (const float*)&vbi;
    const float* pbf = (const float*)&vbf;
    const float* pbc = (const float*)&vbc;
    const float* pbo = (const float*)&vbo;
    const float* pc0 = (const float*)&vc0;
    const float* pmc = (const float*)&vmc;

    float h1[4], c1[4];
#pragma unroll
    for (int j = 0; j < 4; ++j) {
        float xi = gate[0][j] + pbi[j];
        float xf = gate[1][j] + pbf[j];
        float xc = gate[2][j] + pbc[j];
        float xo = gate[3][j] + pbo[j];
        float I = 1.f / (1.f + __expf(-xi));
        float F = 1.f / (1.f + __expf(-xf));
        float C = tanhf(xc) * pmc[j];
        float O = 1.f / (1.f + __expf(-xo));
        c1[j] = F * pc0[j] + I * C;
        h1[j] = O * tanhf(c1[j]);
    }
    out[i] = make_float4(h1[0], h1[1], h1[2], h1[3]);
    out[BH / 4 + i] = make_float4(c1[0], c1[1], c1[2], c1[3]);
}

extern "C" void kernel_launch(void* const* d_in, const int* in_sizes, int n_in,
                              void* d_out, int out_size, void* d_ws, size_t ws_size,
                              hipStream_t stream) {
    const float* x   = (const float*)d_in[0];
    const float* h0  = (const float*)d_in[1];
    const float* c0  = (const float*)d_in[2];
    const float* wxi = (const float*)d_in[3];
    const float* wxf = (const float*)d_in[4];
    const float* wxc = (const float*)d_in[5];
    const float* wxo = (const float*)d_in[6];
    const float* whi = (const float*)d_in[7];
    const float* whf = (const float*)d_in[8];
    const float* whc = (const float*)d_in[9];
    const float* who = (const float*)d_in[10];
    const float* bi  = (const float*)d_in[11];
    const float* bf  = (const float*)d_in[12];
    const float* bc  = (const float*)d_in[13];
    const float* bo  = (const float*)d_in[14];
    const float* mI  = (const float*)d_in[15];
    const float* mF  = (const float*)d_in[16];
    const float* mC  = (const float*)d_in[17];
    const float* mO  = (const float*)d_in[18];
    const float* mCell = (const float*)d_in[19];

    // ws layout: 18*1M bf16 = 36 MB | part: 8*BH bf16 = 32 MB
    __hip_bfloat16* ws18 = (__hip_bfloat16*)d_ws;
    __hip_bfloat16* part = ws18 + (size_t)18 * WSEG;

    prep_all_k<<<dim3(WSEG / 4 / 256, 18), dim3(256), 0, stream>>>(
        wxi, wxf, wxc, wxo, whi, whf, whc, who, x, h0, mI, mF, mC, mO,
        (uint2*)ws18);

    gemm_split<<<dim3(BDIM / 128, HDIM / 128, 8), dim3(256), 0, stream>>>(
        ws18, part);

    combine_k<<<dim3(BH / 4 / 256), dim3(256), 0, stream>>>(
        (const uint2*)part, bi, bf, bc, bo, c0, mCell, (float4*)d_out);
}